// Round 6
// baseline (485.225 us; speedup 1.0000x reference)
//
#include <hip/hip_runtime.h>
#include <hip/hip_bf16.h>
#include <math.h>

// Problem constants
#define BB 8
#define SS 512
#define DD 768
#define LL 200

typedef __attribute__((ext_vector_type(8))) short bf16x8;
typedef __attribute__((ext_vector_type(4))) float f32x4;

__device__ inline short f2bf(float f) {
    unsigned u = __builtin_bit_cast(unsigned, f);
    unsigned r = (u + 0x7FFFu + ((u >> 16) & 1u)) >> 16;
    return (short)r;
}

// ---------------------------------------------------------------------------
// MFMA bf16 GEMM: C[M,N] = epi(A_bf16[M,lda] @ B + bias)
//  - A: bf16 row-major, K contiguous, zero-padded to Kp=ceil64(K) (buffers!)
//  - TB=true : B is bf16 [N][ldb] row-major (B^T layout)
//    TB=false: B is f32  [K][ldb] row-major (converted in staging)
//  - dual-B (TB=false only): for output cols >= nsplit use Bv2/bias2
// Tile 64x64, K-step 64, 4 waves, register prefetch.
// ---------------------------------------------------------------------------
#define LDP2 72   // LDS row pitch in bf16 (144 B = 9*16B odd -> ~conflict-free)

template<int EPI, bool TB>
__global__ __launch_bounds__(256) void mgemm_k(
    const short* __restrict__ A, int lda,
    const void* __restrict__ Bv, int ldb,
    const float* __restrict__ bias,
    const void* __restrict__ Bv2, const float* __restrict__ bias2, int nsplit,
    float* __restrict__ Cf, int ldc,
    short* __restrict__ Cb, int ldcb,
    int M, int N, int K)
{
    __shared__ __align__(16) short As[64 * LDP2];
    __shared__ __align__(16) short Bs[64 * LDP2];
    const int tid = threadIdx.x;
    const int bm = blockIdx.y * 64;
    const int bn = blockIdx.x * 64;
    int bnb = bn;
    if (!TB && bn >= nsplit) { Bv = Bv2; bias = bias2; bnb = bn - nsplit; }
    const int w = tid >> 6, lane = tid & 63, g = lane >> 4, ln = lane & 15;
    const int Kp = (K + 63) & ~63;
    const int nt = Kp >> 6;

    const int ar = tid >> 2, ac = tid & 3;   // A / B(TB): row 0..63, 32B chunk 0..3
    const int bkk = tid >> 2, bc = tid & 3;  // B(f32): k-row 0..63, 16-float chunk

    f32x4 acc[4];
    #pragma unroll
    for (int i = 0; i < 4; ++i) acc[i] = (f32x4){0.f, 0.f, 0.f, 0.f};

    bf16x8 aR0 = {0,0,0,0,0,0,0,0}, aR1 = {0,0,0,0,0,0,0,0};
    bf16x8 bR0 = {0,0,0,0,0,0,0,0}, bR1 = {0,0,0,0,0,0,0,0};
    float  bF[16];
    #pragma unroll
    for (int j = 0; j < 16; ++j) bF[j] = 0.f;

    const int gmS = bm + ar;
    const bool aOk = (gmS < M);

    auto fetchA = [&](int k0) {
        if (aOk) {
            const short* p = A + (size_t)gmS * lda + k0 + ac * 16;
            aR0 = *(const bf16x8*)p;
            aR1 = *(const bf16x8*)(p + 8);
        }
    };
    auto fetchB = [&](int k0) {
        if (TB) {
            const short* Bt = (const short*)Bv;
            int gn = bn + ar;
            if (gn < N) {
                const short* p = Bt + (size_t)gn * ldb + k0 + ac * 16;
                bR0 = *(const bf16x8*)p;
                bR1 = *(const bf16x8*)(p + 8);
            }
        } else {
            const float* Bp = (const float*)Bv;
            int gk = k0 + bkk;
            int n0 = bnb + bc * 16;
            int gn0 = bn + bc * 16;
            if (gk < K) {
                const float* p = Bp + (size_t)gk * ldb + n0;
                if (gn0 + 16 <= N) {
                    #pragma unroll
                    for (int q = 0; q < 4; ++q) {
                        float4 x = *(const float4*)(p + q * 4);
                        bF[q*4+0]=x.x; bF[q*4+1]=x.y; bF[q*4+2]=x.z; bF[q*4+3]=x.w;
                    }
                } else {
                    #pragma unroll
                    for (int j = 0; j < 16; ++j) bF[j] = (gn0 + j < N) ? p[j] : 0.f;
                }
            } else {
                #pragma unroll
                for (int j = 0; j < 16; ++j) bF[j] = 0.f;
            }
        }
    };

    fetchA(0);
    fetchB(0);

    for (int t = 0; t < nt; ++t) {
        {
            short* pa = As + ar * LDP2 + ac * 16;
            *(bf16x8*)pa = aR0;
            *(bf16x8*)(pa + 8) = aR1;
        }
        if (TB) {
            short* pb = Bs + ar * LDP2 + ac * 16;
            *(bf16x8*)pb = bR0;
            *(bf16x8*)(pb + 8) = bR1;
        } else {
            #pragma unroll
            for (int j = 0; j < 16; ++j)
                Bs[(bc * 16 + j) * LDP2 + bkk] = f2bf(bF[j]);
        }
        __syncthreads();

        if (t + 1 < nt) {
            int k0 = (t + 1) << 6;
            fetchA(k0);
            fetchB(k0);
        }

        #pragma unroll
        for (int ks = 0; ks < 2; ++ks) {
            bf16x8 a = *(const bf16x8*)(As + (w * 16 + ln) * LDP2 + ks * 32 + g * 8);
            #pragma unroll
            for (int nb = 0; nb < 4; ++nb) {
                bf16x8 b = *(const bf16x8*)(Bs + (nb * 16 + ln) * LDP2 + ks * 32 + g * 8);
                acc[nb] = __builtin_amdgcn_mfma_f32_16x16x32_bf16(a, b, acc[nb], 0, 0, 0);
            }
        }
        __syncthreads();
    }

    #pragma unroll
    for (int nb = 0; nb < 4; ++nb) {
        int gn = bn + nb * 16 + ln;
        float bv = (bias && gn < N) ? bias[bnb + nb * 16 + ln] : 0.f;
        #pragma unroll
        for (int r = 0; r < 4; ++r) {
            int gm = bm + w * 16 + g * 4 + r;
            if (gm < M && gn < N) {
                float v = acc[nb][r] + bv;
                if (EPI == 1) v = (v >= 0.f) ? v : 0.2f * v;
                else if (EPI == 2) v = 1.f / (1.f + expf(-v));
                if (Cf) Cf[(size_t)gm * ldc + gn] = v;
                if (Cb) Cb[(size_t)gm * ldcb + gn] = f2bf(v);
            }
        }
    }
}

// ---------------------------------------------------------------------------
// prep: conv weights -> kappa-ordered bf16 [208][WP], kappa = kj*16+ki,
//       bias folded at (kj=0, ki=9); label_adj -> bf16 padded [200][256]
// ---------------------------------------------------------------------------
#define WP 168     // 336 B row pitch = 21 x 16B (odd) -> conflict-free b128
#define TP 24      // winT pitch: 48 B = 3 x 16B (odd)
#define WTR 217    // winT rows (guard to col 212)
#define WROWS 208
#define APAD 256   // K-pitch for K=200 operands (BK=64 tail-safe)

__global__ void prep_k(const float* __restrict__ cw, const float* __restrict__ cb,
                       const float* __restrict__ adj,
                       short* __restrict__ wkg, short* __restrict__ adj_bf)
{
    int idx = blockIdx.x * blockDim.x + threadIdx.x;
    if (idx < WROWS * WP) {
        int o = idx / WP, kk = idx % WP;
        int kj = kk >> 4, ki = kk & 15;
        float v = 0.f;
        if (o < LL && kj < 9) {
            if (ki < 9) v = cw[o * 81 + ki * 9 + kj];
            else if (ki == 9 && kj == 0) v = cb[o];
        }
        wkg[idx] = f2bf(v);
        return;
    }
    idx -= WROWS * WP;
    if (idx < LL * APAD) {
        int r = idx / APAD, c = idx % APAD;
        adj_bf[idx] = f2bf(c < LL ? adj[r * LL + c] : 0.f);
    }
}

// fused colsum + rsqrt + normalized adjacency: An[i][j] = bf16(A[j,i]d_i d_j)
__global__ void ca_k(const float* __restrict__ A, short* __restrict__ An)
{
    int i = blockIdx.x;
    int j = threadIdx.x;     // 256
    float si = 0.f, sj = 0.f;
    for (int l = 0; l < LL; ++l) {
        si += A[l * LL + i];
        if (j < LL) sj += A[l * LL + j];
    }
    float di = (si > 0.f) ? (1.f / sqrtf(si)) : 0.f;
    float dj = (sj > 0.f) ? (1.f / sqrtf(sj)) : 0.f;
    float v = (j < LL) ? A[j * LL + i] * di * dj : 0.f;
    An[i * APAD + j] = f2bf(v);
}

// l1-normalize columns of X [L,D] (axis=L), emit bf16
__global__ void l1norm_cols_bf_k(const float* __restrict__ X, short* __restrict__ Xb)
{
    int dcol = blockIdx.x * blockDim.x + threadIdx.x;
    if (dcol >= DD) return;
    float s = 0.f;
    for (int l = 0; l < LL; ++l) s += fabsf(X[l * DD + dcol]);
    float inv = 1.f / fmaxf(s, 1e-12f);
    for (int l = 0; l < LL; ++l) Xb[l * DD + dcol] = f2bf(X[l * DD + dcol] * inv);
}

// doc l1 denom: denom[b,d] = max(sum_s |doc[b,s,d]|, 1e-12)
__global__ void docsum_k(const float* __restrict__ doc, float* __restrict__ denom)
{
    int dc = blockIdx.x, b = blockIdx.y;
    int dx = threadIdx.x & 63, sy = threadIdx.x >> 6;
    int d = dc * 64 + dx;
    float s = 0.f;
    for (int t = sy; t < SS; t += 4)
        s += fabsf(doc[((size_t)b * SS + t) * DD + d]);
    __shared__ float red[4][64];
    red[sy][dx] = s;
    __syncthreads();
    if (sy == 0)
        denom[b * DD + d] = fmaxf(red[0][dx] + red[1][dx] + red[2][dx] + red[3][dx], 1e-12f);
}

// doc_nb = bf16(doc / denom), fully parallel float4
__global__ void docbf_k(const float* __restrict__ doc, const float* __restrict__ denom,
                        short* __restrict__ docb)
{
    int gid = blockIdx.x * blockDim.x + threadIdx.x;
    if (gid >= BB * SS * DD / 4) return;
    size_t base = (size_t)gid * 4;
    int d = (int)(base % DD);
    int b = (int)(base / ((size_t)SS * DD));
    float4 v = *(const float4*)(doc + base);
    float4 dn = *(const float4*)(denom + b * DD + d);
    short4 o;
    o.x = f2bf(v.x / dn.x);
    o.y = f2bf(v.y / dn.y);
    o.z = f2bf(v.z / dn.z);
    o.w = f2bf(v.w / dn.w);
    *(short4*)(docb + base) = o;
}

// ---------------------------------------------------------------------------
// Fused conv(9x9,200ch)+bias -> max(channel,width) -> tanh.
// 512 threads = 8 waves = 8 consecutive s positions (wave <-> position);
// 2 waves/SIMD for MFMA latency hiding. W + 16-row window staged once/block.
// GEMM per position: C[o,l] = sum_kappa W[o,kappa] * P[kappa,l],
//   kappa = kj*16+ki; mfma_16x16x32: MFMA j covers kj = {2j, 2j+(g>>1)}.
//   A frag: Wk[(mt*16+ln)*WP + j*32 + g*8]               (one b128)
//   B frag: winT[(l + 2j + (g>>1))*TP + (g&1)*8]         (one b128)
// Bias folded via constant-1 tap at (kj=0, ki=9). C row = g*4+r, col = ln.
// ---------------------------------------------------------------------------
__global__ __launch_bounds__(512, 2) void conv_max_k(
    const float* __restrict__ wla,   // [4096, 200]
    const short* __restrict__ wkg,   // [208][WP] bf16
    float* __restrict__ gate)        // [4096]
{
    extern __shared__ short smem[];
    short* Wk   = smem;                       // 208*168 = 34944 shorts
    short* winT = Wk + WROWS * WP;            // 8*217*24 = 41664 shorts
    short* wbf  = winT + 8 * WTR * TP;        // 16*216  =  3456 shorts
    // total 80064 shorts = 160128 B

    const int blk = blockIdx.x;               // 512 blocks
    const int b = blk >> 6;                   // 64 blocks per batch
    const int s0 = (blk & 63) << 3;           // 8 positions per block
    const int tid = threadIdx.x;

    // stage W (16B copies; 34944/8 = 4368 int4s)
    {
        const int4* src = (const int4*)wkg;
        int4* dst = (int4*)Wk;
        for (int i = tid; i < WROWS * WP / 8; i += 512) dst[i] = src[i];
    }
    // stage window rows s0-4..s0+11 (16), cols -4..211 as bf16
    for (int idx = tid; idx < 16 * 216; idx += 512) {
        int r = idx / 216, c = idx % 216;
        int sr = s0 - 4 + r, col = c - 4;
        float v = 0.f;
        if (sr >= 0 && sr < SS && col >= 0 && col < LL)
            v = wla[((size_t)b * SS + sr) * LL + col];
        wbf[idx] = f2bf(v);
    }
    __syncthreads();
    // per-position transposed windows winT[p][r][ki] (+ bias-1 at ki=9)
    for (int idx = tid; idx < 8 * WTR; idx += 512) {
        int p = idx / WTR, r = idx % WTR;
        short vals[16];
        #pragma unroll
        for (int i = 0; i < 9; ++i) vals[i] = (r < 216) ? wbf[(p + i) * 216 + r] : (short)0;
        vals[9] = (short)0x3F80;   // 1.0 (bias tap)
        #pragma unroll
        for (int i = 10; i < 16; ++i) vals[i] = 0;
        short* dstp = winT + (p * WTR + r) * TP;
        *(bf16x8*)dstp = *(const bf16x8*)vals;
        *(bf16x8*)(dstp + 8) = *(const bf16x8*)(vals + 8);
    }
    __syncthreads();

    const int w = tid >> 6;        // wave = position 0..7
    const int lane = tid & 63;
    const int g = lane >> 4;       // k-group 0..3
    const int ln = lane & 15;      // row/col-in-tile
    const short* WT = winT + w * WTR * TP;

    // preload ALL A fragments (13 strips x 5 MFMAs)
    bf16x8 Af[13][5];
    #pragma unroll
    for (int s = 0; s < 13; ++s)
        #pragma unroll
        for (int j = 0; j < 5; ++j)
            Af[s][j] = *(const bf16x8*)(Wk + (s * 16 + ln) * WP + j * 32 + g * 8);

    float lm = -INFINITY;

    auto loadB = [&](int nt, bf16x8 (&Bf)[5]) {
        #pragma unroll
        for (int j = 0; j < 5; ++j)
            Bf[j] = *(const bf16x8*)(WT + (nt * 16 + ln + 2 * j + (g >> 1)) * TP + (g & 1) * 8);
    };
    auto compute = [&](int nt, const bf16x8 (&Bf)[5]) {
        #pragma unroll
        for (int s = 0; s < 13; ++s) {
            f32x4 acc = {0.f, 0.f, 0.f, 0.f};
            #pragma unroll
            for (int j = 0; j < 5; ++j)
                acc = __builtin_amdgcn_mfma_f32_16x16x32_bf16(Af[s][j], Bf[j], acc, 0, 0, 0);
            float t = fmaxf(fmaxf(acc[0], acc[1]), fmaxf(acc[2], acc[3]));
            bool ok = (s < 12 || g < 2) && (nt < 12 || ln < 8);  // o<200, l<200
            lm = ok ? fmaxf(lm, t) : lm;
        }
    };

    bf16x8 B0[5], B1[5];
    loadB(0, B0);
    for (int nt = 0; nt < 12; nt += 2) {
        loadB(nt + 1, B1);
        compute(nt, B0);
        loadB(nt + 2, B0);
        compute(nt + 1, B1);
    }
    compute(12, B0);

    #pragma unroll
    for (int off = 32; off > 0; off >>= 1)
        lm = fmaxf(lm, __shfl_xor(lm, off, 64));
    if (lane == 0) gate[((size_t)b << 9) + s0 + w] = tanhf(lm);
}

// ---------------------------------------------------------------------------
// h_enc two-phase: partials over 64-row s-chunks; final sum fused into final2
// ---------------------------------------------------------------------------
__global__ void henc_part_k(const float* __restrict__ doc, const float* __restrict__ gate,
                            float* __restrict__ hpart)
{
    int dc = blockIdx.x, sc = blockIdx.y, b = blockIdx.z;
    int dx = threadIdx.x & 63, sy = threadIdx.x >> 6;
    int d = dc * 64 + dx;
    float s = 0.f;
    for (int t = sy; t < 64; t += 4) {
        int srow = sc * 64 + t;
        s = fmaf(doc[((size_t)b * SS + srow) * DD + d], gate[b * SS + srow], s);
    }
    __shared__ float red[4][64];
    red[sy][dx] = s;
    __syncthreads();
    if (sy == 0)
        hpart[((size_t)b * 8 + sc) * DD + d] = red[0][dx] + red[1][dx] + red[2][dx] + red[3][dx];
}

// final: h[b,:] = sum_sc hpart / denom; out[b,l] = sigmoid(h @ W[:,l] + bias[l])
__global__ void final2_k(const float* __restrict__ hpart, const float* __restrict__ denom,
                         const float* __restrict__ W, const float* __restrict__ bias,
                         float* __restrict__ out)
{
    int b = blockIdx.x, tid = threadIdx.x;
    __shared__ float hb[DD];
    for (int idx = tid; idx < DD; idx += 256) {
        float s = 0.f;
        #pragma unroll
        for (int sc = 0; sc < 8; ++sc) s += hpart[((size_t)b * 8 + sc) * DD + idx];
        hb[idx] = s / denom[b * DD + idx];
    }
    __syncthreads();
    int l = tid;
    if (l < LL) {
        float acc = bias[l];
        for (int d = 0; d < DD; ++d) acc = fmaf(hb[d], W[d * LL + l], acc);
        out[b * LL + l] = 1.f / (1.f + expf(-acc));
    }
}

__global__ void loss_k(const float* __restrict__ out, const float* __restrict__ labels,
                       float* __restrict__ loss_out)
{
    float s = 0.f;
    for (int i = threadIdx.x; i < BB * LL; i += 256) {
        float p = out[i];
        p = fminf(fmaxf(p, 1e-7f), 1.f - 1e-7f);
        float y = labels[i];
        s += y * logf(p) + (1.f - y) * logf(1.f - p);
    }
    #pragma unroll
    for (int off = 32; off > 0; off >>= 1) s += __shfl_down(s, off, 64);
    __shared__ float ws[4];
    if ((threadIdx.x & 63) == 0) ws[threadIdx.x >> 6] = s;
    __syncthreads();
    if (threadIdx.x == 0)
        loss_out[0] = -(ws[0] + ws[1] + ws[2] + ws[3]) / (float)(BB * LL);
}

// ---------------------------------------------------------------------------
static void mgemm(hipStream_t st, int epi, bool tb,
                  const short* A, int lda, const void* B, int ldb,
                  const float* bias, const void* B2, const float* bias2, int nsplit,
                  float* Cf, int ldc, short* Cb, int ldcb,
                  int M, int N, int K)
{
    dim3 g((N + 63) / 64, (M + 63) / 64);
    if (!tb) {
        if (epi == 0)      mgemm_k<0, false><<<g, 256, 0, st>>>(A, lda, B, ldb, bias, B2, bias2, nsplit, Cf, ldc, Cb, ldcb, M, N, K);
        else if (epi == 1) mgemm_k<1, false><<<g, 256, 0, st>>>(A, lda, B, ldb, bias, B2, bias2, nsplit, Cf, ldc, Cb, ldcb, M, N, K);
        else               mgemm_k<2, false><<<g, 256, 0, st>>>(A, lda, B, ldb, bias, B2, bias2, nsplit, Cf, ldc, Cb, ldcb, M, N, K);
    } else {
        if (epi == 0)      mgemm_k<0, true><<<g, 256, 0, st>>>(A, lda, B, ldb, bias, B2, bias2, nsplit, Cf, ldc, Cb, ldcb, M, N, K);
        else if (epi == 1) mgemm_k<1, true><<<g, 256, 0, st>>>(A, lda, B, ldb, bias, B2, bias2, nsplit, Cf, ldc, Cb, ldcb, M, N, K);
        else               mgemm_k<2, true><<<g, 256, 0, st>>>(A, lda, B, ldb, bias, B2, bias2, nsplit, Cf, ldc, Cb, ldcb, M, N, K);
    }
}

extern "C" void kernel_launch(void* const* d_in, const int* in_sizes, int n_in,
                              void* d_out, int out_size, void* d_ws, size_t ws_size,
                              hipStream_t stream)
{
    const float* doc_emb   = (const float*)d_in[0];
    const float* labels    = (const float*)d_in[1];
    const float* label_emb = (const float*)d_in[2];
    const float* label_adj = (const float*)d_in[3];
    const float* w_gcn3    = (const float*)d_in[4];
    const float* w_gcn5    = (const float*)d_in[5];
    const float* w_ll1     = (const float*)d_in[6];
    const float* b_ll1     = (const float*)d_in[7];
    const float* w_ll2     = (const float*)d_in[8];
    const float* b_ll2     = (const float*)d_in[9];
    const float* w_lin     = (const float*)d_in[10];
    const float* b_lin     = (const float*)d_in[11];
    const float* conv_w    = (const float*)d_in[12];
    const float* conv_b    = (const float*)d_in[13];
    const float* w_lin1    = (const float*)d_in[14];
    const float* b_lin1    = (const float*)d_in[15];

    float* out = (float*)d_out;   // [B*L] + [1]

    char* p = (char*)d_ws;
    auto alloc = [&](size_t bytes) { void* r = p; p += (bytes + 15) & ~(size_t)15; return r; };
    short* wkg       = (short*)alloc(WROWS * WP * 2);
    short* adj_bf    = (short*)alloc(200 * APAD * 2);
    short* E2_bf     = (short*)alloc(200 * 768 * 2);
    float* le_f      = (float*)alloc(200 * 768 * 4);
    short* le_cat_bf = (short*)alloc(200 * 1536 * 2);   // [le | d_le]
    short* qk_bf     = (short*)alloc(200 * 1536 * 2);   // [q | k]
    float* Amat      = (float*)alloc(200 * 200 * 4);
    short* Anorm_bf  = (short*)alloc(200 * APAD * 2);
    short* G_bf      = (short*)alloc(200 * 768 * 2);
    float* le_out_f  = (float*)alloc(200 * 768 * 4);
    short* le_out_bf = (short*)alloc(200 * 768 * 2);
    float* denom     = (float*)alloc(BB * DD * 4);
    short* doc_nb    = (short*)alloc((size_t)BB * SS * DD * 2);
    float* wla       = (float*)alloc((size_t)BB * SS * LL * 4);
    float* gatev     = (float*)alloc(BB * SS * 4);
    float* hpart     = (float*)alloc(BB * 8 * DD * 4);

    const int BIG = 1 << 30;

    // prep (conv weights kappa-order + bias fold, adj pad)
    prep_k<<<(WROWS * WP + LL * APAD + 255) / 256, 256, 0, stream>>>(
        conv_w, conv_b, label_adj, wkg, adj_bf);
    // E2 = adj @ emb
    mgemm(stream, 0, false, adj_bf, APAD, label_emb, DD, nullptr, nullptr, nullptr, BIG,
          nullptr, 0, E2_bf, DD, LL, DD, LL);
    // le = leaky(E2 @ W3)
    mgemm(stream, 1, false, E2_bf, DD, w_gcn3, DD, nullptr, nullptr, nullptr, BIG,
          le_f, DD, le_cat_bf, 1536, LL, DD, DD);
    // [q|k] = le @ [w_ll1 | w_ll2] + [b1|b2]   (fused dual-B, N=1536)
    mgemm(stream, 0, false, le_cat_bf, 1536, w_ll1, DD, b_ll1, w_ll2, b_ll2, DD,
          nullptr, 0, qk_bf, 1536, LL, 2 * DD, DD);
    // A = sigmoid(q @ k^T)
    mgemm(stream, 2, true, qk_bf, 1536, qk_bf + DD, 1536, nullptr, nullptr, nullptr, BIG,
          Amat, LL, nullptr, 0, LL, LL, DD);
    // fused colsum + rsqrt + normalized adjacency
    ca_k<<<LL, 256, 0, stream>>>(Amat, Anorm_bf);
    // G = Anorm @ le
    mgemm(stream, 0, false, Anorm_bf, APAD, le_f, DD, nullptr, nullptr, nullptr, BIG,
          nullptr, 0, G_bf, DD, LL, DD, LL);
    // d_le = leaky(G @ W5)
    mgemm(stream, 1, false, G_bf, DD, w_gcn5, DD, nullptr, nullptr, nullptr, BIG,
          nullptr, 0, le_cat_bf + DD, 1536, LL, DD, DD);
    // le_out = le_cat @ w_lin + b_lin
    mgemm(stream, 0, false, le_cat_bf, 1536, w_lin, DD, b_lin, nullptr, nullptr, BIG,
          le_out_f, DD, nullptr, 0, LL, DD, 2 * DD);
    l1norm_cols_bf_k<<<(DD + 255) / 256, 256, 0, stream>>>(le_out_f, le_out_bf);
    // doc l1 norm (two-phase) -> denom + bf16 doc
    docsum_k<<<dim3(12, 8), 256, 0, stream>>>(doc_emb, denom);
    docbf_k<<<(BB * SS * DD / 4 + 255) / 256, 256, 0, stream>>>(doc_emb, denom, doc_nb);
    // wla = doc_n @ le_out^T
    mgemm(stream, 0, true, doc_nb, DD, le_out_bf, DD, nullptr, nullptr, nullptr, BIG,
          wla, LL, nullptr, 0, BB * SS, LL, DD);
    // conv + max + tanh  (8 positions/block, 512 thr, 160128 B dynamic LDS)
    (void)hipFuncSetAttribute((const void*)conv_max_k,
                              hipFuncAttributeMaxDynamicSharedMemorySize, 160128);
    conv_max_k<<<512, 512, 160128, stream>>>(wla, wkg, gatev);
    // h_enc partials
    henc_part_k<<<dim3(12, 8, 8), 256, 0, stream>>>(doc_emb, gatev, hpart);
    // fused h_enc finalize + final linear + sigmoid
    final2_k<<<BB, 256, 0, stream>>>(hpart, denom, w_lin1, b_lin1, out);
    loss_k<<<1, 256, 0, stream>>>(out, labels, out + BB * LL);
}

// Round 7
// 326.032 us; speedup vs baseline: 1.4883x; 1.4883x over previous
//
#include <hip/hip_runtime.h>
#include <hip/hip_bf16.h>
#include <math.h>

// Problem constants
#define BB 8
#define SS 512
#define DD 768
#define LL 200

typedef __attribute__((ext_vector_type(8))) short bf16x8;
typedef __attribute__((ext_vector_type(4))) float f32x4;

__device__ inline short f2bf(float f) {
    unsigned u = __builtin_bit_cast(unsigned, f);
    unsigned r = (u + 0x7FFFu + ((u >> 16) & 1u)) >> 16;
    return (short)r;
}

// ---------------------------------------------------------------------------
// MFMA bf16 GEMM: C[M,N] = epi(A_bf16[M,lda] @ B + bias)
//  - A: bf16 row-major, K contiguous, zero-padded to Kp=ceil64(K) (buffers!)
//  - TB=true : B is bf16 [N][ldb] row-major (B^T layout)
//    TB=false: B is f32  [K][ldb] row-major (converted in staging)
//  - dual-B (TB=false only): for output cols >= nsplit use Bv2/bias2
// Tile 64x64, K-step 64, 4 waves, register prefetch.
// ---------------------------------------------------------------------------
#define LDP2 72   // LDS row pitch in bf16 (144 B = 9*16B odd -> ~conflict-free)

template<int EPI, bool TB>
__global__ __launch_bounds__(256) void mgemm_k(
    const short* __restrict__ A, int lda,
    const void* __restrict__ Bv, int ldb,
    const float* __restrict__ bias,
    const void* __restrict__ Bv2, const float* __restrict__ bias2, int nsplit,
    float* __restrict__ Cf, int ldc,
    short* __restrict__ Cb, int ldcb,
    int M, int N, int K)
{
    __shared__ __align__(16) short As[64 * LDP2];
    __shared__ __align__(16) short Bs[64 * LDP2];
    const int tid = threadIdx.x;
    const int bm = blockIdx.y * 64;
    const int bn = blockIdx.x * 64;
    int bnb = bn;
    if (!TB && bn >= nsplit) { Bv = Bv2; bias = bias2; bnb = bn - nsplit; }
    const int w = tid >> 6, lane = tid & 63, g = lane >> 4, ln = lane & 15;
    const int Kp = (K + 63) & ~63;
    const int nt = Kp >> 6;

    const int ar = tid >> 2, ac = tid & 3;   // A / B(TB): row 0..63, 32B chunk 0..3
    const int bkk = tid >> 2, bc = tid & 3;  // B(f32): k-row 0..63, 16-float chunk

    f32x4 acc[4];
    #pragma unroll
    for (int i = 0; i < 4; ++i) acc[i] = (f32x4){0.f, 0.f, 0.f, 0.f};

    bf16x8 aR0 = {0,0,0,0,0,0,0,0}, aR1 = {0,0,0,0,0,0,0,0};
    bf16x8 bR0 = {0,0,0,0,0,0,0,0}, bR1 = {0,0,0,0,0,0,0,0};
    float  bF[16];
    #pragma unroll
    for (int j = 0; j < 16; ++j) bF[j] = 0.f;

    const int gmS = bm + ar;
    const bool aOk = (gmS < M);

    auto fetchA = [&](int k0) {
        if (aOk) {
            const short* p = A + (size_t)gmS * lda + k0 + ac * 16;
            aR0 = *(const bf16x8*)p;
            aR1 = *(const bf16x8*)(p + 8);
        }
    };
    auto fetchB = [&](int k0) {
        if (TB) {
            const short* Bt = (const short*)Bv;
            int gn = bn + ar;
            if (gn < N) {
                const short* p = Bt + (size_t)gn * ldb + k0 + ac * 16;
                bR0 = *(const bf16x8*)p;
                bR1 = *(const bf16x8*)(p + 8);
            }
        } else {
            const float* Bp = (const float*)Bv;
            int gk = k0 + bkk;
            int n0 = bnb + bc * 16;
            int gn0 = bn + bc * 16;
            if (gk < K) {
                const float* p = Bp + (size_t)gk * ldb + n0;
                if (gn0 + 16 <= N) {
                    #pragma unroll
                    for (int q = 0; q < 4; ++q) {
                        float4 x = *(const float4*)(p + q * 4);
                        bF[q*4+0]=x.x; bF[q*4+1]=x.y; bF[q*4+2]=x.z; bF[q*4+3]=x.w;
                    }
                } else {
                    #pragma unroll
                    for (int j = 0; j < 16; ++j) bF[j] = (gn0 + j < N) ? p[j] : 0.f;
                }
            } else {
                #pragma unroll
                for (int j = 0; j < 16; ++j) bF[j] = 0.f;
            }
        }
    };

    fetchA(0);
    fetchB(0);

    for (int t = 0; t < nt; ++t) {
        {
            short* pa = As + ar * LDP2 + ac * 16;
            *(bf16x8*)pa = aR0;
            *(bf16x8*)(pa + 8) = aR1;
        }
        if (TB) {
            short* pb = Bs + ar * LDP2 + ac * 16;
            *(bf16x8*)pb = bR0;
            *(bf16x8*)(pb + 8) = bR1;
        } else {
            #pragma unroll
            for (int j = 0; j < 16; ++j)
                Bs[(bc * 16 + j) * LDP2 + bkk] = f2bf(bF[j]);
        }
        __syncthreads();

        if (t + 1 < nt) {
            int k0 = (t + 1) << 6;
            fetchA(k0);
            fetchB(k0);
        }

        #pragma unroll
        for (int ks = 0; ks < 2; ++ks) {
            bf16x8 a = *(const bf16x8*)(As + (w * 16 + ln) * LDP2 + ks * 32 + g * 8);
            #pragma unroll
            for (int nb = 0; nb < 4; ++nb) {
                bf16x8 b = *(const bf16x8*)(Bs + (nb * 16 + ln) * LDP2 + ks * 32 + g * 8);
                acc[nb] = __builtin_amdgcn_mfma_f32_16x16x32_bf16(a, b, acc[nb], 0, 0, 0);
            }
        }
        __syncthreads();
    }

    #pragma unroll
    for (int nb = 0; nb < 4; ++nb) {
        int gn = bn + nb * 16 + ln;
        float bv = (bias && gn < N) ? bias[bnb + nb * 16 + ln] : 0.f;
        #pragma unroll
        for (int r = 0; r < 4; ++r) {
            int gm = bm + w * 16 + g * 4 + r;
            if (gm < M && gn < N) {
                float v = acc[nb][r] + bv;
                if (EPI == 1) v = (v >= 0.f) ? v : 0.2f * v;
                else if (EPI == 2) v = 1.f / (1.f + expf(-v));
                if (Cf) Cf[(size_t)gm * ldc + gn] = v;
                if (Cb) Cb[(size_t)gm * ldcb + gn] = f2bf(v);
            }
        }
    }
}

// ---------------------------------------------------------------------------
// prep: conv weights -> kappa-ordered bf16 [208][WP], kappa = kj*16+ki,
//       bias folded at (kj=0, ki=9); label_adj -> bf16 padded [200][256]
// ---------------------------------------------------------------------------
#define WP 168     // 336 B row pitch = 21 x 16B (odd) -> conflict-free b128
#define TP 24      // winT pitch: 48 B = 3 x 16B (odd)
#define WTR 217    // winT rows (guard to col 212)
#define WROWS 208
#define APAD 256   // K-pitch for K=200 operands (BK=64 tail-safe)

__global__ void prep_k(const float* __restrict__ cw, const float* __restrict__ cb,
                       const float* __restrict__ adj,
                       short* __restrict__ wkg, short* __restrict__ adj_bf)
{
    int idx = blockIdx.x * blockDim.x + threadIdx.x;
    if (idx < WROWS * WP) {
        int o = idx / WP, kk = idx % WP;
        int kj = kk >> 4, ki = kk & 15;
        float v = 0.f;
        if (o < LL && kj < 9) {
            if (ki < 9) v = cw[o * 81 + ki * 9 + kj];
            else if (ki == 9 && kj == 0) v = cb[o];
        }
        wkg[idx] = f2bf(v);
        return;
    }
    idx -= WROWS * WP;
    if (idx < LL * APAD) {
        int r = idx / APAD, c = idx % APAD;
        adj_bf[idx] = f2bf(c < LL ? adj[r * LL + c] : 0.f);
    }
}

// fused colsum + rsqrt + normalized adjacency: An[i][j] = bf16(A[j,i]d_i d_j)
__global__ void ca_k(const float* __restrict__ A, short* __restrict__ An)
{
    int i = blockIdx.x;
    int j = threadIdx.x;     // 256
    float si = 0.f, sj = 0.f;
    for (int l = 0; l < LL; ++l) {
        si += A[l * LL + i];
        if (j < LL) sj += A[l * LL + j];
    }
    float di = (si > 0.f) ? (1.f / sqrtf(si)) : 0.f;
    float dj = (sj > 0.f) ? (1.f / sqrtf(sj)) : 0.f;
    float v = (j < LL) ? A[j * LL + i] * di * dj : 0.f;
    An[i * APAD + j] = f2bf(v);
}

// l1-normalize columns of X [L,D] (axis=L), emit bf16
__global__ void l1norm_cols_bf_k(const float* __restrict__ X, short* __restrict__ Xb)
{
    int dcol = blockIdx.x * blockDim.x + threadIdx.x;
    if (dcol >= DD) return;
    float s = 0.f;
    for (int l = 0; l < LL; ++l) s += fabsf(X[l * DD + dcol]);
    float inv = 1.f / fmaxf(s, 1e-12f);
    for (int l = 0; l < LL; ++l) Xb[l * DD + dcol] = f2bf(X[l * DD + dcol] * inv);
}

// doc l1 denom: denom[b,d] = max(sum_s |doc[b,s,d]|, 1e-12)
__global__ void docsum_k(const float* __restrict__ doc, float* __restrict__ denom)
{
    int dc = blockIdx.x, b = blockIdx.y;
    int dx = threadIdx.x & 63, sy = threadIdx.x >> 6;
    int d = dc * 64 + dx;
    float s = 0.f;
    for (int t = sy; t < SS; t += 4)
        s += fabsf(doc[((size_t)b * SS + t) * DD + d]);
    __shared__ float red[4][64];
    red[sy][dx] = s;
    __syncthreads();
    if (sy == 0)
        denom[b * DD + d] = fmaxf(red[0][dx] + red[1][dx] + red[2][dx] + red[3][dx], 1e-12f);
}

// doc_nb = bf16(doc / denom), fully parallel float4
__global__ void docbf_k(const float* __restrict__ doc, const float* __restrict__ denom,
                        short* __restrict__ docb)
{
    int gid = blockIdx.x * blockDim.x + threadIdx.x;
    if (gid >= BB * SS * DD / 4) return;
    size_t base = (size_t)gid * 4;
    int d = (int)(base % DD);
    int b = (int)(base / ((size_t)SS * DD));
    float4 v = *(const float4*)(doc + base);
    float4 dn = *(const float4*)(denom + b * DD + d);
    short4 o;
    o.x = f2bf(v.x / dn.x);
    o.y = f2bf(v.y / dn.y);
    o.z = f2bf(v.z / dn.z);
    o.w = f2bf(v.w / dn.w);
    *(short4*)(docb + base) = o;
}

// ---------------------------------------------------------------------------
// Fused conv(9x9,200ch)+bias -> max(channel,width) -> tanh.
// 512 threads = 8 waves = 4 positions x 2 o-halves (wave pair <-> position).
// 2 waves/SIMD with per-wave VGPR <= ~220 (Af[7][5]=140): NO spill by design.
// GEMM per position: C[o,l] = sum_kappa W[o,kappa] * P[kappa,l],
//   kappa = kj*16+ki; mfma_16x16x32: MFMA j covers kj = {2j, 2j+(g>>1)}.
//   A frag: Wk[(st*16+ln)*WP + j*32 + g*8]               (one b128)
//   B frag: winT[(l + 2j + (g>>1))*TP + (g&1)*8]         (one b128)
// Bias folded via constant-1 tap at (kj=0, ki=9). C row = g*4+r, col = ln.
// o-half h=0: strips 0..6, h=1: strips 7..12; cross-wave max via LDS.
// ---------------------------------------------------------------------------
__global__ __launch_bounds__(512, 1) void conv_max_k(
    const float* __restrict__ wla,   // [4096, 200]
    const short* __restrict__ wkg,   // [208][WP] bf16
    float* __restrict__ gate)        // [4096]
{
    extern __shared__ short smem[];
    short* Wk   = smem;                       // 208*168 = 34944 shorts
    short* winT = Wk + WROWS * WP;            // 4*217*24 = 20832 shorts
    short* wbf  = winT + 4 * WTR * TP;        // 12*216  =  2592 shorts
    // dynamic total 58368 shorts = 116736 B
    __shared__ float wredf[8];

    const int blk = blockIdx.x;               // 1024 blocks
    const int b = blk >> 7;                   // 128 blocks per batch
    const int s0 = (blk & 127) << 2;          // 4 positions per block
    const int tid = threadIdx.x;

    // stage W (16B copies; 34944/8 = 4368 int4s)
    {
        const int4* src = (const int4*)wkg;
        int4* dst = (int4*)Wk;
        for (int i = tid; i < WROWS * WP / 8; i += 512) dst[i] = src[i];
    }
    // stage window rows s0-4..s0+7 (12), cols -4..211 as bf16
    for (int idx = tid; idx < 12 * 216; idx += 512) {
        int r = idx / 216, c = idx % 216;
        int sr = s0 - 4 + r, col = c - 4;
        float v = 0.f;
        if (sr >= 0 && sr < SS && col >= 0 && col < LL)
            v = wla[((size_t)b * SS + sr) * LL + col];
        wbf[idx] = f2bf(v);
    }
    __syncthreads();
    // per-position transposed windows winT[p][r][ki] (+ bias-1 at ki=9)
    for (int idx = tid; idx < 4 * WTR; idx += 512) {
        int p = idx / WTR, r = idx % WTR;
        short vals[16];
        #pragma unroll
        for (int i = 0; i < 9; ++i) vals[i] = (r < 216) ? wbf[(p + i) * 216 + r] : (short)0;
        vals[9] = (short)0x3F80;   // 1.0 (bias tap)
        #pragma unroll
        for (int i = 10; i < 16; ++i) vals[i] = 0;
        short* dstp = winT + (p * WTR + r) * TP;
        *(bf16x8*)dstp = *(const bf16x8*)vals;
        *(bf16x8*)(dstp + 8) = *(const bf16x8*)(vals + 8);
    }
    __syncthreads();

    const int w = tid >> 6;        // wave 0..7
    const int p = w >> 1;          // position 0..3
    const int h = w & 1;           // o-half: 0 -> strips 0..6, 1 -> strips 7..12
    const int lane = tid & 63;
    const int g = lane >> 4;       // k-group 0..3
    const int ln = lane & 15;      // row/col-in-tile
    const short* WT = winT + p * WTR * TP;

    // preload A fragments for this wave's strips (<=7 strips x 5 MFMAs = 140 VGPR)
    bf16x8 Af[7][5];
    #pragma unroll
    for (int s = 0; s < 7; ++s) {
        int st = h * 7 + s;
        if (st > 12) st = 12;      // clamp (h=1,s=6 unused, masked below)
        #pragma unroll
        for (int j = 0; j < 5; ++j)
            Af[s][j] = *(const bf16x8*)(Wk + (st * 16 + ln) * WP + j * 32 + g * 8);
    }

    float lm = -INFINITY;

    auto loadB = [&](int nt, bf16x8 (&Bf)[5]) {
        #pragma unroll
        for (int j = 0; j < 5; ++j)
            Bf[j] = *(const bf16x8*)(WT + (nt * 16 + ln + 2 * j + (g >> 1)) * TP + (g & 1) * 8);
    };
    auto compute = [&](int nt, const bf16x8 (&Bf)[5]) {
        #pragma unroll
        for (int s = 0; s < 7; ++s) {
            if (h == 0 || s < 6) {           // wave-uniform; h=1 has 6 strips
                int st = h * 7 + s;
                f32x4 acc = {0.f, 0.f, 0.f, 0.f};
                #pragma unroll
                for (int j = 0; j < 5; ++j)
                    acc = __builtin_amdgcn_mfma_f32_16x16x32_bf16(Af[s][j], Bf[j], acc, 0, 0, 0);
                float t = fmaxf(fmaxf(acc[0], acc[1]), fmaxf(acc[2], acc[3]));
                bool ok = (st < 12 || g < 2) && (nt < 12 || ln < 8);  // o<200, l<200
                lm = ok ? fmaxf(lm, t) : lm;
            }
        }
    };

    bf16x8 B0[5], B1[5];
    loadB(0, B0);
    for (int nt = 0; nt < 12; nt += 2) {
        loadB(nt + 1, B1);
        compute(nt, B0);
        loadB(nt + 2, B0);
        compute(nt + 1, B1);
    }
    compute(12, B0);

    #pragma unroll
    for (int off = 32; off > 0; off >>= 1)
        lm = fmaxf(lm, __shfl_xor(lm, off, 64));
    if (lane == 0) wredf[w] = lm;
    __syncthreads();
    if (tid < 4)
        gate[((size_t)b << 9) + s0 + tid] = tanhf(fmaxf(wredf[2 * tid], wredf[2 * tid + 1]));
}

// ---------------------------------------------------------------------------
// h_enc two-phase: partials over 64-row s-chunks; final sum fused into final2
// ---------------------------------------------------------------------------
__global__ void henc_part_k(const float* __restrict__ doc, const float* __restrict__ gate,
                            float* __restrict__ hpart)
{
    int dc = blockIdx.x, sc = blockIdx.y, b = blockIdx.z;
    int dx = threadIdx.x & 63, sy = threadIdx.x >> 6;
    int d = dc * 64 + dx;
    float s = 0.f;
    for (int t = sy; t < 64; t += 4) {
        int srow = sc * 64 + t;
        s = fmaf(doc[((size_t)b * SS + srow) * DD + d], gate[b * SS + srow], s);
    }
    __shared__ float red[4][64];
    red[sy][dx] = s;
    __syncthreads();
    if (sy == 0)
        hpart[((size_t)b * 8 + sc) * DD + d] = red[0][dx] + red[1][dx] + red[2][dx] + red[3][dx];
}

// final: h[b,:] = sum_sc hpart / denom; out[b,l] = sigmoid(h @ W[:,l] + bias[l])
__global__ void final2_k(const float* __restrict__ hpart, const float* __restrict__ denom,
                         const float* __restrict__ W, const float* __restrict__ bias,
                         float* __restrict__ out)
{
    int b = blockIdx.x, tid = threadIdx.x;
    __shared__ float hb[DD];
    for (int idx = tid; idx < DD; idx += 256) {
        float s = 0.f;
        #pragma unroll
        for (int sc = 0; sc < 8; ++sc) s += hpart[((size_t)b * 8 + sc) * DD + idx];
        hb[idx] = s / denom[b * DD + idx];
    }
    __syncthreads();
    int l = tid;
    if (l < LL) {
        float acc = bias[l];
        for (int d = 0; d < DD; ++d) acc = fmaf(hb[d], W[d * LL + l], acc);
        out[b * LL + l] = 1.f / (1.f + expf(-acc));
    }
}

__global__ void loss_k(const float* __restrict__ out, const float* __restrict__ labels,
                       float* __restrict__ loss_out)
{
    float s = 0.f;
    for (int i = threadIdx.x; i < BB * LL; i += 256) {
        float p = out[i];
        p = fminf(fmaxf(p, 1e-7f), 1.f - 1e-7f);
        float y = labels[i];
        s += y * logf(p) + (1.f - y) * logf(1.f - p);
    }
    #pragma unroll
    for (int off = 32; off > 0; off >>= 1) s += __shfl_down(s, off, 64);
    __shared__ float ws[4];
    if ((threadIdx.x & 63) == 0) ws[threadIdx.x >> 6] = s;
    __syncthreads();
    if (threadIdx.x == 0)
        loss_out[0] = -(ws[0] + ws[1] + ws[2] + ws[3]) / (float)(BB * LL);
}

// ---------------------------------------------------------------------------
static void mgemm(hipStream_t st, int epi, bool tb,
                  const short* A, int lda, const void* B, int ldb,
                  const float* bias, const void* B2, const float* bias2, int nsplit,
                  float* Cf, int ldc, short* Cb, int ldcb,
                  int M, int N, int K)
{
    dim3 g((N + 63) / 64, (M + 63) / 64);
    if (!tb) {
        if (epi == 0)      mgemm_k<0, false><<<g, 256, 0, st>>>(A, lda, B, ldb, bias, B2, bias2, nsplit, Cf, ldc, Cb, ldcb, M, N, K);
        else if (epi == 1) mgemm_k<1, false><<<g, 256, 0, st>>>(A, lda, B, ldb, bias, B2, bias2, nsplit, Cf, ldc, Cb, ldcb, M, N, K);
        else               mgemm_k<2, false><<<g, 256, 0, st>>>(A, lda, B, ldb, bias, B2, bias2, nsplit, Cf, ldc, Cb, ldcb, M, N, K);
    } else {
        if (epi == 0)      mgemm_k<0, true><<<g, 256, 0, st>>>(A, lda, B, ldb, bias, B2, bias2, nsplit, Cf, ldc, Cb, ldcb, M, N, K);
        else if (epi == 1) mgemm_k<1, true><<<g, 256, 0, st>>>(A, lda, B, ldb, bias, B2, bias2, nsplit, Cf, ldc, Cb, ldcb, M, N, K);
        else               mgemm_k<2, true><<<g, 256, 0, st>>>(A, lda, B, ldb, bias, B2, bias2, nsplit, Cf, ldc, Cb, ldcb, M, N, K);
    }
}

extern "C" void kernel_launch(void* const* d_in, const int* in_sizes, int n_in,
                              void* d_out, int out_size, void* d_ws, size_t ws_size,
                              hipStream_t stream)
{
    const float* doc_emb   = (const float*)d_in[0];
    const float* labels    = (const float*)d_in[1];
    const float* label_emb = (const float*)d_in[2];
    const float* label_adj = (const float*)d_in[3];
    const float* w_gcn3    = (const float*)d_in[4];
    const float* w_gcn5    = (const float*)d_in[5];
    const float* w_ll1     = (const float*)d_in[6];
    const float* b_ll1     = (const float*)d_in[7];
    const float* w_ll2     = (const float*)d_in[8];
    const float* b_ll2     = (const float*)d_in[9];
    const float* w_lin     = (const float*)d_in[10];
    const float* b_lin     = (const float*)d_in[11];
    const float* conv_w    = (const float*)d_in[12];
    const float* conv_b    = (const float*)d_in[13];
    const float* w_lin1    = (const float*)d_in[14];
    const float* b_lin1    = (const float*)d_in[15];

    float* out = (float*)d_out;   // [B*L] + [1]

    char* p = (char*)d_ws;
    auto alloc = [&](size_t bytes) { void* r = p; p += (bytes + 15) & ~(size_t)15; return r; };
    short* wkg       = (short*)alloc(WROWS * WP * 2);
    short* adj_bf    = (short*)alloc(200 * APAD * 2);
    short* E2_bf     = (short*)alloc(200 * 768 * 2);
    float* le_f      = (float*)alloc(200 * 768 * 4);
    short* le_cat_bf = (short*)alloc(200 * 1536 * 2);   // [le | d_le]
    short* qk_bf     = (short*)alloc(200 * 1536 * 2);   // [q | k]
    float* Amat      = (float*)alloc(200 * 200 * 4);
    short* Anorm_bf  = (short*)alloc(200 * APAD * 2);
    short* G_bf      = (short*)alloc(200 * 768 * 2);
    float* le_out_f  = (float*)alloc(200 * 768 * 4);
    short* le_out_bf = (short*)alloc(200 * 768 * 2);
    float* denom     = (float*)alloc(BB * DD * 4);
    short* doc_nb    = (short*)alloc((size_t)BB * SS * DD * 2);
    float* wla       = (float*)alloc((size_t)BB * SS * LL * 4);
    float* gatev     = (float*)alloc(BB * SS * 4);
    float* hpart     = (float*)alloc(BB * 8 * DD * 4);

    const int BIG = 1 << 30;

    // prep (conv weights kappa-order + bias fold, adj pad)
    prep_k<<<(WROWS * WP + LL * APAD + 255) / 256, 256, 0, stream>>>(
        conv_w, conv_b, label_adj, wkg, adj_bf);
    // E2 = adj @ emb
    mgemm(stream, 0, false, adj_bf, APAD, label_emb, DD, nullptr, nullptr, nullptr, BIG,
          nullptr, 0, E2_bf, DD, LL, DD, LL);
    // le = leaky(E2 @ W3)
    mgemm(stream, 1, false, E2_bf, DD, w_gcn3, DD, nullptr, nullptr, nullptr, BIG,
          le_f, DD, le_cat_bf, 1536, LL, DD, DD);
    // [q|k] = le @ [w_ll1 | w_ll2] + [b1|b2]   (fused dual-B, N=1536)
    mgemm(stream, 0, false, le_cat_bf, 1536, w_ll1, DD, b_ll1, w_ll2, b_ll2, DD,
          nullptr, 0, qk_bf, 1536, LL, 2 * DD, DD);
    // A = sigmoid(q @ k^T)
    mgemm(stream, 2, true, qk_bf, 1536, qk_bf + DD, 1536, nullptr, nullptr, nullptr, BIG,
          Amat, LL, nullptr, 0, LL, LL, DD);
    // fused colsum + rsqrt + normalized adjacency
    ca_k<<<LL, 256, 0, stream>>>(Amat, Anorm_bf);
    // G = Anorm @ le
    mgemm(stream, 0, false, Anorm_bf, APAD, le_f, DD, nullptr, nullptr, nullptr, BIG,
          nullptr, 0, G_bf, DD, LL, DD, LL);
    // d_le = leaky(G @ W5)
    mgemm(stream, 1, false, G_bf, DD, w_gcn5, DD, nullptr, nullptr, nullptr, BIG,
          nullptr, 0, le_cat_bf + DD, 1536, LL, DD, DD);
    // le_out = le_cat @ w_lin + b_lin
    mgemm(stream, 0, false, le_cat_bf, 1536, w_lin, DD, b_lin, nullptr, nullptr, BIG,
          le_out_f, DD, nullptr, 0, LL, DD, 2 * DD);
    l1norm_cols_bf_k<<<(DD + 255) / 256, 256, 0, stream>>>(le_out_f, le_out_bf);
    // doc l1 norm (two-phase) -> denom + bf16 doc
    docsum_k<<<dim3(12, 8), 256, 0, stream>>>(doc_emb, denom);
    docbf_k<<<(BB * SS * DD / 4 + 255) / 256, 256, 0, stream>>>(doc_emb, denom, doc_nb);
    // wla = doc_n @ le_out^T
    mgemm(stream, 0, true, doc_nb, DD, le_out_bf, DD, nullptr, nullptr, nullptr, BIG,
          wla, LL, nullptr, 0, BB * SS, LL, DD);
    // conv + max + tanh  (4 positions x 2 o-halves, 512 thr, 116736 B dyn LDS)
    (void)hipFuncSetAttribute((const void*)conv_max_k,
                              hipFuncAttributeMaxDynamicSharedMemorySize, 116736);
    conv_max_k<<<1024, 512, 116736, stream>>>(wla, wkg, gatev);
    // h_enc partials
    henc_part_k<<<dim3(12, 8, 8), 256, 0, stream>>>(doc_emb, gatev, hpart);
    // fused h_enc finalize + final linear + sigmoid
    final2_k<<<BB, 256, 0, stream>>>(hpart, denom, w_lin1, b_lin1, out);
    loss_k<<<1, 256, 0, stream>>>(out, labels, out + BB * LL);
}